// Round 1
// baseline (982.693 us; speedup 1.0000x reference)
//
#include <hip/hip_runtime.h>
#include <float.h>
#include <math.h>

// Problem constants
#define NB 16
#define NN 577
#define NC 384
#define NH 6
#define ND 64
#define NNN 332929          // 577*577
#define RPD2 2209           // 47*47
#define MTOT 9232           // NB*NN
#define SCALE_ 0.125f
#define SZ 3545088ull       // NB*NH*NN*ND (elements)

// ---------------------------------------------------------------------------
// QKV GEMM: out[m][r] = sum_k X[m][k]*W[r][k] + b[r], scattered to Q/K/V in
// (B,H,N,D) layout. M=9232, K=384, R=1152. 64x64 tile, BK=16, 4x4/thread.
// LDS tiles stored k-major (transposed) so inner loop uses float4 reads.
// ---------------------------------------------------------------------------
__global__ __launch_bounds__(256) void qkv_gemm_k(
    const float* __restrict__ X, const float* __restrict__ W,
    const float* __restrict__ bias, float* __restrict__ ws)
{
  __shared__ float As[16 * 68];
  __shared__ float Bs[16 * 68];
  const int tid = threadIdx.x;
  const int m0 = blockIdx.x * 64;
  const int r0 = blockIdx.y * 64;
  const int tx = tid & 15, ty = tid >> 4;
  const int lm = tid >> 2, lk0 = (tid & 3) << 2;
  const bool mvalid = (m0 + lm) < MTOT;
  float acc[4][4] = {};

  for (int k0 = 0; k0 < 384; k0 += 16) {
    float4 av = {0.f, 0.f, 0.f, 0.f};
    if (mvalid) av = *(const float4*)&X[(size_t)(m0 + lm) * 384 + k0 + lk0];
    float4 bv = *(const float4*)&W[(size_t)(r0 + lm) * 384 + k0 + lk0];
    __syncthreads();
    As[(lk0 + 0) * 68 + lm] = av.x;
    As[(lk0 + 1) * 68 + lm] = av.y;
    As[(lk0 + 2) * 68 + lm] = av.z;
    As[(lk0 + 3) * 68 + lm] = av.w;
    Bs[(lk0 + 0) * 68 + lm] = bv.x;
    Bs[(lk0 + 1) * 68 + lm] = bv.y;
    Bs[(lk0 + 2) * 68 + lm] = bv.z;
    Bs[(lk0 + 3) * 68 + lm] = bv.w;
    __syncthreads();
#pragma unroll
    for (int kk = 0; kk < 16; ++kk) {
      float4 a4 = *(const float4*)&As[kk * 68 + 4 * ty];
      float4 b4 = *(const float4*)&Bs[kk * 68 + 4 * tx];
      float a[4] = {a4.x, a4.y, a4.z, a4.w};
      float bl[4] = {b4.x, b4.y, b4.z, b4.w};
#pragma unroll
      for (int i = 0; i < 4; ++i)
#pragma unroll
        for (int j = 0; j < 4; ++j) acc[i][j] += a[i] * bl[j];
    }
  }

  // scatter: r = comp*384 + h*64 + d ; block spans one (comp,h) since r0%64==0
  const int comp = r0 / 384;
  const int hh = (r0 % 384) / 64;
  float* dst = ws + (size_t)comp * SZ;
  float4 bz = *(const float4*)&bias[r0 + 4 * tx];
#pragma unroll
  for (int i = 0; i < 4; ++i) {
    int m = m0 + 4 * ty + i;
    if (m >= MTOT) continue;
    int bb = m / NN, nn = m % NN;
    size_t base = (((size_t)(bb * NH + hh)) * NN + nn) * ND + 4 * tx;
    float4 o;
    o.x = acc[i][0] + bz.x;
    o.y = acc[i][1] + bz.y;
    o.z = acc[i][2] + bz.z;
    o.w = acc[i][3] + bz.w;
    *(float4*)&dst[base] = o;
  }
}

// ---------------------------------------------------------------------------
// Fused attention: one block per (b, h, 32-row q-tile).
// Full 32x577 score tile kept in LDS -> exact softmax, no online rescale.
// ---------------------------------------------------------------------------
#define SROW 584

__global__ __launch_bounds__(256) void attn_k(
    const float* __restrict__ Q, const float* __restrict__ K,
    const float* __restrict__ V, float* __restrict__ O,
    const float* __restrict__ rel_pos, const int* __restrict__ rel_idx,
    const int* __restrict__ mask, const int* __restrict__ patch)
{
  __shared__ float S[32 * SROW];   // 74752 B
  __shared__ float KV[8448];       // K^T stage 64x132 (33792 B) / V stage 128x64
  __shared__ float Qs[32 * ND];    // 8192 B
  __shared__ float relp[RPD2];     // 8836 B

  const int tid = threadIdx.x;
  const int q0 = blockIdx.x * 32;
  const int h = blockIdx.y;
  const int b = blockIdx.z;
  const int bh = b * NH + h;
  const float* Qp = Q + (size_t)bh * NN * ND;
  const float* Kp = K + (size_t)bh * NN * ND;
  const float* Vp = V + (size_t)bh * NN * ND;
  const int pa = *patch;

  for (int i = tid; i < RPD2; i += 256) relp[i] = rel_pos[h * RPD2 + i];
  for (int u = tid; u < 512; u += 256) {   // stage Q tile (zero-pad rows>=577)
    int row = u >> 4, d4 = (u & 15) << 2;
    int gq = q0 + row;
    float4 v = {0.f, 0.f, 0.f, 0.f};
    if (gq < NN) v = *(const float4*)&Qp[(size_t)gq * ND + d4];
    *(float4*)&Qs[row * ND + d4] = v;
  }
  __syncthreads();

  // ---- S = Q K^T (chunks of 128 keys) ----
  {
    const int qg = tid >> 5, kg = tid & 31;
    for (int c = 0; c < 5; ++c) {
      const int kbase = c * 128;
      for (int u = tid; u < 2048; u += 256) {  // stage K transposed [d][k], stride 132
        int kr = u >> 4, d4 = (u & 15) << 2;
        int gk = kbase + kr;
        float4 v = {0.f, 0.f, 0.f, 0.f};
        if (gk < NN) v = *(const float4*)&Kp[(size_t)gk * ND + d4];
        KV[(d4 + 0) * 132 + kr] = v.x;
        KV[(d4 + 1) * 132 + kr] = v.y;
        KV[(d4 + 2) * 132 + kr] = v.z;
        KV[(d4 + 3) * 132 + kr] = v.w;
      }
      __syncthreads();
      float acc[4][4] = {};
      for (int d0 = 0; d0 < ND; d0 += 4) {
        float qa[4][4], kb[4][4];
#pragma unroll
        for (int i = 0; i < 4; ++i) {
          float4 t = *(const float4*)&Qs[(4 * qg + i) * ND + d0];
          qa[i][0] = t.x; qa[i][1] = t.y; qa[i][2] = t.z; qa[i][3] = t.w;
        }
#pragma unroll
        for (int dd = 0; dd < 4; ++dd) {
          float4 t = *(const float4*)&KV[(d0 + dd) * 132 + 4 * kg];
          kb[dd][0] = t.x; kb[dd][1] = t.y; kb[dd][2] = t.z; kb[dd][3] = t.w;
        }
#pragma unroll
        for (int i = 0; i < 4; ++i)
#pragma unroll
          for (int dd = 0; dd < 4; ++dd)
#pragma unroll
            for (int j = 0; j < 4; ++j)
              acc[i][j] += qa[i][dd] * kb[dd][j];
      }
#pragma unroll
      for (int i = 0; i < 4; ++i)
#pragma unroll
        for (int j = 0; j < 4; ++j) {
          int col = kbase + 4 * kg + j;
          if (col < SROW) S[(4 * qg + i) * SROW + col] = acc[i][j];
        }
      __syncthreads();
    }
  }

  // ---- scale + rel-pos bias + mask ----
  for (int q = 0; q < 32; ++q) {
    const int gq = q0 + q;
    if (gq >= NN) break;
    const size_t mrow = (size_t)b * NNN + (size_t)gq * NN;
    const int birow = (gq - 1) * 576 - 1;     // + k gives (gq-1)*576 + (k-1)
    for (int k = tid; k < NN; k += 256) {
      float s = S[q * SROW + k] * SCALE_;
      if (pa && gq >= 1 && k >= 1) s += relp[rel_idx[birow + k]];
      if (mask[mrow + k] == 0) s = -FLT_MAX;
      S[q * SROW + k] = s;
    }
  }
  __syncthreads();

  // ---- row softmax: 8 lanes per row ----
  {
    const int row = tid >> 3, l8 = tid & 7;
    const int gq = q0 + row;
    float mx = -FLT_MAX;
    if (gq < NN)
      for (int k = l8; k < NN; k += 8) mx = fmaxf(mx, S[row * SROW + k]);
    mx = fmaxf(mx, __shfl_xor(mx, 1));
    mx = fmaxf(mx, __shfl_xor(mx, 2));
    mx = fmaxf(mx, __shfl_xor(mx, 4));
    float sum = 0.f;
    if (gq < NN)
      for (int k = l8; k < NN; k += 8) {
        float e = __expf(S[row * SROW + k] - mx);
        S[row * SROW + k] = e;
        sum += e;
      }
    sum += __shfl_xor(sum, 1);
    sum += __shfl_xor(sum, 2);
    sum += __shfl_xor(sum, 4);
    float inv = 1.f / sum;
    if (gq < NN)
      for (int k = l8; k < NN; k += 8) S[row * SROW + k] *= inv;
    if (l8 < 7) S[row * SROW + NN + l8] = 0.f;  // zero pad cols 577..583
  }
  __syncthreads();

  // ---- O = P V ----
  {
    const int qg = tid >> 5, dg = tid & 31;
    float acc[4][2] = {};
    for (int c = 0; c < 5; ++c) {
      const int kbase = c * 128;
      for (int u = tid; u < 2048; u += 256) {  // stage V [k][d], zero-pad
        int kr = u >> 4, d4 = (u & 15) << 2;
        int gk = kbase + kr;
        float4 v = {0.f, 0.f, 0.f, 0.f};
        if (gk < NN) v = *(const float4*)&Vp[(size_t)gk * ND + d4];
        *(float4*)&KV[kr * ND + d4] = v;
      }
      __syncthreads();
      const int klim = (c == 4) ? 68 : 128;    // 512+68 covers 577 (pad cols are 0)
      for (int k0 = 0; k0 < klim; k0 += 4) {
        float p[4][4];
#pragma unroll
        for (int i = 0; i < 4; ++i) {
          float4 t = *(const float4*)&S[(4 * qg + i) * SROW + kbase + k0];
          p[i][0] = t.x; p[i][1] = t.y; p[i][2] = t.z; p[i][3] = t.w;
        }
        float2 v2[4];
#pragma unroll
        for (int j = 0; j < 4; ++j)
          v2[j] = *(const float2*)&KV[(k0 + j) * ND + 2 * dg];
#pragma unroll
        for (int i = 0; i < 4; ++i)
#pragma unroll
          for (int j = 0; j < 4; ++j) {
            acc[i][0] += p[i][j] * v2[j].x;
            acc[i][1] += p[i][j] * v2[j].y;
          }
      }
      __syncthreads();
    }
#pragma unroll
    for (int i = 0; i < 4; ++i) {
      int gq = q0 + 4 * qg + i;
      if (gq < NN) {
        float2 o;
        o.x = acc[i][0];
        o.y = acc[i][1];
        *(float2*)&O[(size_t)bh * NN * ND + (size_t)gq * ND + 2 * dg] = o;
      }
    }
  }
}

// ---------------------------------------------------------------------------
// Projection GEMM: out[m][r] = sum_c O'(m,c)*W[r][c] + b[r]
// O'(m,c) reads O in (B,H,N,D) layout with c = h*64+d.
// ---------------------------------------------------------------------------
__global__ __launch_bounds__(256) void proj_gemm_k(
    const float* __restrict__ O, const float* __restrict__ W,
    const float* __restrict__ bias, float* __restrict__ out)
{
  __shared__ float As[16 * 68];
  __shared__ float Bs[16 * 68];
  const int tid = threadIdx.x;
  const int m0 = blockIdx.x * 64;
  const int r0 = blockIdx.y * 64;
  const int tx = tid & 15, ty = tid >> 4;
  const int lm = tid >> 2, lk0 = (tid & 3) << 2;
  const int m = m0 + lm;
  const bool mv = m < MTOT;
  int bb = 0, nn = 0;
  if (mv) { bb = m / NN; nn = m % NN; }
  float acc[4][4] = {};

  for (int k0 = 0; k0 < 384; k0 += 16) {
    const int c = k0 + lk0;
    float4 av = {0.f, 0.f, 0.f, 0.f};
    if (mv) {
      int hh = c >> 6, d0 = c & 63;
      av = *(const float4*)&O[(((size_t)(bb * NH + hh)) * NN + nn) * ND + d0];
    }
    float4 bv = *(const float4*)&W[(size_t)(r0 + lm) * 384 + c];
    __syncthreads();
    As[(lk0 + 0) * 68 + lm] = av.x;
    As[(lk0 + 1) * 68 + lm] = av.y;
    As[(lk0 + 2) * 68 + lm] = av.z;
    As[(lk0 + 3) * 68 + lm] = av.w;
    Bs[(lk0 + 0) * 68 + lm] = bv.x;
    Bs[(lk0 + 1) * 68 + lm] = bv.y;
    Bs[(lk0 + 2) * 68 + lm] = bv.z;
    Bs[(lk0 + 3) * 68 + lm] = bv.w;
    __syncthreads();
#pragma unroll
    for (int kk = 0; kk < 16; ++kk) {
      float4 a4 = *(const float4*)&As[kk * 68 + 4 * ty];
      float4 b4 = *(const float4*)&Bs[kk * 68 + 4 * tx];
      float a[4] = {a4.x, a4.y, a4.z, a4.w};
      float bl[4] = {b4.x, b4.y, b4.z, b4.w};
#pragma unroll
      for (int i = 0; i < 4; ++i)
#pragma unroll
        for (int j = 0; j < 4; ++j) acc[i][j] += a[i] * bl[j];
    }
  }

  float4 bz = *(const float4*)&bias[r0 + 4 * tx];
#pragma unroll
  for (int i = 0; i < 4; ++i) {
    int mm = m0 + 4 * ty + i;
    if (mm >= MTOT) continue;
    float4 o;
    o.x = acc[i][0] + bz.x;
    o.y = acc[i][1] + bz.y;
    o.z = acc[i][2] + bz.z;
    o.w = acc[i][3] + bz.w;
    *(float4*)&out[(size_t)mm * NC + r0 + 4 * tx] = o;
  }
}

// ---------------------------------------------------------------------------
extern "C" void kernel_launch(void* const* d_in, const int* in_sizes, int n_in,
                              void* d_out, int out_size, void* d_ws, size_t ws_size,
                              hipStream_t stream) {
  const float* x       = (const float*)d_in[0];
  const float* qkv_w   = (const float*)d_in[1];
  const float* qkv_b   = (const float*)d_in[2];
  const float* proj_w  = (const float*)d_in[3];
  const float* proj_b  = (const float*)d_in[4];
  const float* rel_pos = (const float*)d_in[5];
  const int*   rel_idx = (const int*)d_in[6];
  const int*   mask    = (const int*)d_in[7];
  const int*   patch   = (const int*)d_in[8];
  float* out = (float*)d_out;
  float* ws  = (float*)d_ws;

  float* Qw = ws;
  float* Kw = ws + SZ;
  float* Vw = ws + 2 * SZ;
  float* Ow = ws + 3 * SZ;

  qkv_gemm_k<<<dim3(145, 18), 256, 0, stream>>>(x, qkv_w, qkv_b, ws);
  attn_k<<<dim3(19, NH, NB), 256, 0, stream>>>(Qw, Kw, Vw, Ow, rel_pos, rel_idx,
                                               mask, patch);
  proj_gemm_k<<<dim3(145, 6), 256, 0, stream>>>(Ow, proj_w, proj_b, out);
}

// Round 2
// 453.710 us; speedup vs baseline: 2.1659x; 2.1659x over previous
//
#include <hip/hip_runtime.h>
#include <float.h>
#include <math.h>

// Problem constants
#define NB 16
#define NN 577
#define NC 384
#define NH 6
#define ND 64
#define NNN 332929          // 577*577
#define RPD2 2209           // 47*47
#define MTOT 9232           // NB*NN
#define SCALE_ 0.125f
#define SZ 3545088ull       // NB*NH*NN*ND (elements)
#define NEGBIG -3.0e38f

// ---------------------------------------------------------------------------
// QKV GEMM: out[m][r] = sum_k X[m][k]*W[r][k] + b[r], scattered to Q/K/V in
// (B,H,N,D) layout. M=9232, K=384, R=1152. 64x64 tile, BK=16, 4x4/thread.
// ---------------------------------------------------------------------------
__global__ __launch_bounds__(256) void qkv_gemm_k(
    const float* __restrict__ X, const float* __restrict__ W,
    const float* __restrict__ bias, float* __restrict__ ws)
{
  __shared__ float As[16 * 68];
  __shared__ float Bs[16 * 68];
  const int tid = threadIdx.x;
  const int m0 = blockIdx.x * 64;
  const int r0 = blockIdx.y * 64;
  const int tx = tid & 15, ty = tid >> 4;
  const int lm = tid >> 2, lk0 = (tid & 3) << 2;
  const bool mvalid = (m0 + lm) < MTOT;
  float acc[4][4] = {};

  for (int k0 = 0; k0 < 384; k0 += 16) {
    float4 av = {0.f, 0.f, 0.f, 0.f};
    if (mvalid) av = *(const float4*)&X[(size_t)(m0 + lm) * 384 + k0 + lk0];
    float4 bv = *(const float4*)&W[(size_t)(r0 + lm) * 384 + k0 + lk0];
    __syncthreads();
    As[(lk0 + 0) * 68 + lm] = av.x;
    As[(lk0 + 1) * 68 + lm] = av.y;
    As[(lk0 + 2) * 68 + lm] = av.z;
    As[(lk0 + 3) * 68 + lm] = av.w;
    Bs[(lk0 + 0) * 68 + lm] = bv.x;
    Bs[(lk0 + 1) * 68 + lm] = bv.y;
    Bs[(lk0 + 2) * 68 + lm] = bv.z;
    Bs[(lk0 + 3) * 68 + lm] = bv.w;
    __syncthreads();
#pragma unroll
    for (int kk = 0; kk < 16; ++kk) {
      float4 a4 = *(const float4*)&As[kk * 68 + 4 * ty];
      float4 b4 = *(const float4*)&Bs[kk * 68 + 4 * tx];
      float a[4] = {a4.x, a4.y, a4.z, a4.w};
      float bl[4] = {b4.x, b4.y, b4.z, b4.w};
#pragma unroll
      for (int i = 0; i < 4; ++i)
#pragma unroll
        for (int j = 0; j < 4; ++j) acc[i][j] += a[i] * bl[j];
    }
  }

  const int comp = r0 / 384;
  const int hh = (r0 % 384) / 64;
  float* dst = ws + (size_t)comp * SZ;
  float4 bz = *(const float4*)&bias[r0 + 4 * tx];
#pragma unroll
  for (int i = 0; i < 4; ++i) {
    int m = m0 + 4 * ty + i;
    if (m >= MTOT) continue;
    int bb = m / NN, nn = m % NN;
    size_t base = (((size_t)(bb * NH + hh)) * NN + nn) * ND + 4 * tx;
    float4 o;
    o.x = acc[i][0] + bz.x;
    o.y = acc[i][1] + bz.y;
    o.z = acc[i][2] + bz.z;
    o.w = acc[i][3] + bz.w;
    *(float4*)&dst[base] = o;
  }
}

// ---------------------------------------------------------------------------
// Pack mask int32 -> bitmask. One 64-lane wave per (b,q) row, ballot per 64 k.
// pm[row*20 + w] bit (k&31) of word (k>>5).
// ---------------------------------------------------------------------------
__global__ __launch_bounds__(256) void pack_mask_k(const int* __restrict__ mask,
                                                   unsigned* __restrict__ pm)
{
  const int wid = (blockIdx.x * 256 + threadIdx.x) >> 6;  // row = b*577+q
  const int lane = threadIdx.x & 63;
  if (wid >= MTOT) return;
  const int* mr = mask + (size_t)wid * NN;
#pragma unroll
  for (int c = 0; c < 10; ++c) {
    int k = c * 64 + lane;
    int v = (k < NN) ? mr[k] : 0;
    unsigned long long bal = __ballot(v != 0);
    if (lane == 0) pm[wid * 20 + 2 * c] = (unsigned)bal;
    if (lane == 1) pm[wid * 20 + 2 * c + 1] = (unsigned)(bal >> 32);
  }
}

// ---------------------------------------------------------------------------
// Flash attention: block = (64 q-rows, h, b). Online softmax over 10 chunks
// of 64 keys. LDS ~51.4KB -> 3 blocks/CU.
// ---------------------------------------------------------------------------
__global__ __launch_bounds__(256, 3) void attn_k(
    const float* __restrict__ Q, const float* __restrict__ K,
    const float* __restrict__ V, float* __restrict__ O,
    const float* __restrict__ rel_pos, const int* __restrict__ rel_idx,
    const unsigned* __restrict__ pmask, const int* __restrict__ patch)
{
  __shared__ float Qs[64 * 64];    // 16384 B (scale folded)
  __shared__ float S[64 * 66];     // 16896 B
  __shared__ float KV[64 * 68];    // 17408 B: K^T stride 66 / V linear stride 68
  __shared__ float mrow[64], lrow[64], frow[64];

  const int tid = threadIdx.x;
  const int q0 = blockIdx.x * 64;
  const int h = blockIdx.y;
  const int b = blockIdx.z;
  const int bh = b * NH + h;
  const float* Qp = Q + (size_t)bh * NN * ND;
  const float* Kp = K + (size_t)bh * NN * ND;
  const float* Vp = V + (size_t)bh * NN * ND;
  const int pa = *patch;

  // stage Q (scaled), init stats
  for (int u = tid; u < 1024; u += 256) {
    int row = u >> 4, d4 = (u & 15) << 2;
    int gq = q0 + row;
    float4 v = {0.f, 0.f, 0.f, 0.f};
    if (gq < NN) {
      v = *(const float4*)&Qp[(size_t)gq * ND + d4];
      v.x *= SCALE_; v.y *= SCALE_; v.z *= SCALE_; v.w *= SCALE_;
    }
    *(float4*)&Qs[row * 64 + d4] = v;
  }
  if (tid < 64) { mrow[tid] = NEGBIG; lrow[tid] = 0.f; }

  float accO[8][2] = {};
  const int qg = tid >> 5;         // 8 row-groups of 8
  const int kg = tid & 31;         // QK: 2 keys ; PV: 2 dims

  for (int ch = 0; ch < 10; ++ch) {
    const int kbase = ch * 64;

    // ---- stage K^T (stride 66) ----
    __syncthreads();
    for (int u = tid; u < 1024; u += 256) {
      int kr = u >> 4, d4 = (u & 15) << 2;
      int gk = kbase + kr;
      float4 v = {0.f, 0.f, 0.f, 0.f};
      if (gk < NN) v = *(const float4*)&Kp[(size_t)gk * ND + d4];
      KV[(d4 + 0) * 66 + kr] = v.x;
      KV[(d4 + 1) * 66 + kr] = v.y;
      KV[(d4 + 2) * 66 + kr] = v.z;
      KV[(d4 + 3) * 66 + kr] = v.w;
    }
    __syncthreads();

    // ---- S = Q K^T ----
    {
      float acc2[8][2] = {};
      for (int d0 = 0; d0 < ND; d0 += 4) {
        float2 ka[4];
#pragma unroll
        for (int dd = 0; dd < 4; ++dd)
          ka[dd] = *(const float2*)&KV[(d0 + dd) * 66 + 2 * kg];
#pragma unroll
        for (int i = 0; i < 8; ++i) {
          float4 q = *(const float4*)&Qs[(8 * qg + i) * 64 + d0];
          acc2[i][0] += q.x * ka[0].x + q.y * ka[1].x + q.z * ka[2].x + q.w * ka[3].x;
          acc2[i][1] += q.x * ka[0].y + q.y * ka[1].y + q.z * ka[2].y + q.w * ka[3].y;
        }
      }
#pragma unroll
      for (int i = 0; i < 8; ++i)
        *(float2*)&S[(8 * qg + i) * 66 + 2 * kg] = make_float2(acc2[i][0], acc2[i][1]);
    }
    __syncthreads();

    // ---- stage V (linear, stride 68) + bias/mask/online-softmax ----
    for (int u = tid; u < 1024; u += 256) {
      int kr = u >> 4, d4 = (u & 15) << 2;
      int gk = kbase + kr;
      float4 v = {0.f, 0.f, 0.f, 0.f};
      if (gk < NN) v = *(const float4*)&Vp[(size_t)gk * ND + d4];
      *(float4*)&KV[kr * 68 + d4] = v;
    }
    {
      const int row = tid >> 2, l4 = tid & 3;
      const int gq = q0 + row;
      const bool rv = gq < NN;
      unsigned w0 = 0, w1 = 0;
      if (rv) {
        const unsigned* mwr = pmask + ((size_t)b * NN + gq) * 20 + (ch << 1);
        w0 = mwr[0]; w1 = mwr[1];
      }
      const int birow = (gq - 1) * 576 - 1;
      float sv[16];
      float cmax = NEGBIG;
#pragma unroll
      for (int t = 0; t < 16; ++t) {
        const int cl = 4 * t + l4;
        const int k = kbase + cl;
        float s = S[row * 66 + cl];
        if (rv) {
          if (k < NN) {
            if (pa && gq >= 1 && k >= 1)
              s += rel_pos[h * RPD2 + rel_idx[birow + k]];
            unsigned wv = (cl & 32) ? w1 : w0;
            if (!((wv >> (k & 31)) & 1u)) s = NEGBIG;
          } else s = NEGBIG;
        } else s = 0.f;
        sv[t] = s;
        cmax = fmaxf(cmax, s);
      }
      cmax = fmaxf(cmax, __shfl_xor(cmax, 1));
      cmax = fmaxf(cmax, __shfl_xor(cmax, 2));
      float m_old = mrow[row];
      float m_new = fmaxf(m_old, cmax);
      float fx = __expf(m_old - m_new);
      float csum = 0.f;
#pragma unroll
      for (int t = 0; t < 16; ++t) {
        float e = __expf(sv[t] - m_new);
        csum += e;
        S[row * 66 + 4 * t + l4] = e;
      }
      csum += __shfl_xor(csum, 1);
      csum += __shfl_xor(csum, 2);
      if (l4 == 0) {
        mrow[row] = m_new;
        frow[row] = fx;
        lrow[row] = lrow[row] * fx + csum;
      }
    }
    __syncthreads();

    // ---- O = O*f + P V ----
    {
#pragma unroll
      for (int i = 0; i < 8; ++i) {
        float fx = frow[8 * qg + i];
        accO[i][0] *= fx;
        accO[i][1] *= fx;
      }
      for (int k0 = 0; k0 < 64; k0 += 2) {
        float2 v0 = *(const float2*)&KV[k0 * 68 + 2 * kg];
        float2 v1 = *(const float2*)&KV[(k0 + 1) * 68 + 2 * kg];
#pragma unroll
        for (int i = 0; i < 8; ++i) {
          float2 p = *(const float2*)&S[(8 * qg + i) * 66 + k0];
          accO[i][0] += p.x * v0.x + p.y * v1.x;
          accO[i][1] += p.x * v0.y + p.y * v1.y;
        }
      }
    }
  }
  __syncthreads();

  // ---- write O ----
#pragma unroll
  for (int i = 0; i < 8; ++i) {
    int gq = q0 + 8 * qg + i;
    if (gq < NN) {
      float inv = 1.f / lrow[8 * qg + i];
      float2 o = make_float2(accO[i][0] * inv, accO[i][1] * inv);
      *(float2*)&O[((size_t)bh * NN + gq) * ND + 2 * kg] = o;
    }
  }
}

// ---------------------------------------------------------------------------
// Projection GEMM
// ---------------------------------------------------------------------------
__global__ __launch_bounds__(256) void proj_gemm_k(
    const float* __restrict__ O, const float* __restrict__ W,
    const float* __restrict__ bias, float* __restrict__ out)
{
  __shared__ float As[16 * 68];
  __shared__ float Bs[16 * 68];
  const int tid = threadIdx.x;
  const int m0 = blockIdx.x * 64;
  const int r0 = blockIdx.y * 64;
  const int tx = tid & 15, ty = tid >> 4;
  const int lm = tid >> 2, lk0 = (tid & 3) << 2;
  const int m = m0 + lm;
  const bool mv = m < MTOT;
  int bb = 0, nn = 0;
  if (mv) { bb = m / NN; nn = m % NN; }
  float acc[4][4] = {};

  for (int k0 = 0; k0 < 384; k0 += 16) {
    const int c = k0 + lk0;
    float4 av = {0.f, 0.f, 0.f, 0.f};
    if (mv) {
      int hh = c >> 6, d0 = c & 63;
      av = *(const float4*)&O[(((size_t)(bb * NH + hh)) * NN + nn) * ND + d0];
    }
    float4 bv = *(const float4*)&W[(size_t)(r0 + lm) * 384 + c];
    __syncthreads();
    As[(lk0 + 0) * 68 + lm] = av.x;
    As[(lk0 + 1) * 68 + lm] = av.y;
    As[(lk0 + 2) * 68 + lm] = av.z;
    As[(lk0 + 3) * 68 + lm] = av.w;
    Bs[(lk0 + 0) * 68 + lm] = bv.x;
    Bs[(lk0 + 1) * 68 + lm] = bv.y;
    Bs[(lk0 + 2) * 68 + lm] = bv.z;
    Bs[(lk0 + 3) * 68 + lm] = bv.w;
    __syncthreads();
#pragma unroll
    for (int kk = 0; kk < 16; ++kk) {
      float4 a4 = *(const float4*)&As[kk * 68 + 4 * ty];
      float4 b4 = *(const float4*)&Bs[kk * 68 + 4 * tx];
      float a[4] = {a4.x, a4.y, a4.z, a4.w};
      float bl[4] = {b4.x, b4.y, b4.z, b4.w};
#pragma unroll
      for (int i = 0; i < 4; ++i)
#pragma unroll
        for (int j = 0; j < 4; ++j) acc[i][j] += a[i] * bl[j];
    }
  }

  float4 bz = *(const float4*)&bias[r0 + 4 * tx];
#pragma unroll
  for (int i = 0; i < 4; ++i) {
    int mm = m0 + 4 * ty + i;
    if (mm >= MTOT) continue;
    float4 o;
    o.x = acc[i][0] + bz.x;
    o.y = acc[i][1] + bz.y;
    o.z = acc[i][2] + bz.z;
    o.w = acc[i][3] + bz.w;
    *(float4*)&out[(size_t)mm * NC + r0 + 4 * tx] = o;
  }
}

// ---------------------------------------------------------------------------
extern "C" void kernel_launch(void* const* d_in, const int* in_sizes, int n_in,
                              void* d_out, int out_size, void* d_ws, size_t ws_size,
                              hipStream_t stream) {
  const float* x       = (const float*)d_in[0];
  const float* qkv_w   = (const float*)d_in[1];
  const float* qkv_b   = (const float*)d_in[2];
  const float* proj_w  = (const float*)d_in[3];
  const float* proj_b  = (const float*)d_in[4];
  const float* rel_pos = (const float*)d_in[5];
  const int*   rel_idx = (const int*)d_in[6];
  const int*   mask    = (const int*)d_in[7];
  const int*   patch   = (const int*)d_in[8];
  float* out = (float*)d_out;
  float* ws  = (float*)d_ws;

  float* Qw = ws;
  float* Kw = ws + SZ;
  float* Vw = ws + 2 * SZ;
  float* Ow = ws + 3 * SZ;
  unsigned* pm = (unsigned*)(ws + 4 * SZ);   // 9232*20 words

  pack_mask_k<<<dim3((MTOT * 64 + 255) / 256), 256, 0, stream>>>(mask, pm);
  qkv_gemm_k<<<dim3(145, 18), 256, 0, stream>>>(x, qkv_w, qkv_b, ws);
  attn_k<<<dim3(10, NH, NB), 256, 0, stream>>>(Qw, Kw, Vw, Ow, rel_pos, rel_idx,
                                               pm, patch);
  proj_gemm_k<<<dim3(145, 6), 256, 0, stream>>>(Ow, proj_w, proj_b, out);
}

// Round 3
// 321.267 us; speedup vs baseline: 3.0588x; 1.4123x over previous
//
#include <hip/hip_runtime.h>
#include <float.h>
#include <math.h>

// Problem constants
#define NB 16
#define NN 577
#define NC 384
#define NH 6
#define ND 64
#define NNN 332929          // 577*577
#define RPD2 2209           // 47*47
#define MTOT 9232           // NB*NN
#define SCALE_ 0.125f
#define SZ 3545088ull       // NB*NH*NN*ND (elements)
#define NEGBIG -3.0e38f
#define BSTRIDE 580         // bias table row stride (ushort)

typedef __attribute__((ext_vector_type(8))) short bf16x8;
typedef __attribute__((ext_vector_type(4))) float f32x4;

#define MFMA16(a, b, c) __builtin_amdgcn_mfma_f32_16x16x32_bf16(a, b, c, 0, 0, 0)

static __device__ __forceinline__ unsigned short f2bf(float f) {
  unsigned u = __float_as_uint(f);
  u += 0x7fff + ((u >> 16) & 1);
  return (unsigned short)(u >> 16);
}
static __device__ __forceinline__ float bf2f(unsigned short h) {
  return __uint_as_float((unsigned)h << 16);
}

// ---------------------------------------------------------------------------
// QKV GEMM (fp32, unchanged): scatter to Q/K/V in (B,H,N,D) layout.
// ---------------------------------------------------------------------------
__global__ __launch_bounds__(256) void qkv_gemm_k(
    const float* __restrict__ X, const float* __restrict__ W,
    const float* __restrict__ bias, float* __restrict__ ws)
{
  __shared__ float As[16 * 68];
  __shared__ float Bs[16 * 68];
  const int tid = threadIdx.x;
  const int m0 = blockIdx.x * 64;
  const int r0 = blockIdx.y * 64;
  const int tx = tid & 15, ty = tid >> 4;
  const int lm = tid >> 2, lk0 = (tid & 3) << 2;
  const bool mvalid = (m0 + lm) < MTOT;
  float acc[4][4] = {};

  for (int k0 = 0; k0 < 384; k0 += 16) {
    float4 av = {0.f, 0.f, 0.f, 0.f};
    if (mvalid) av = *(const float4*)&X[(size_t)(m0 + lm) * 384 + k0 + lk0];
    float4 bv = *(const float4*)&W[(size_t)(r0 + lm) * 384 + k0 + lk0];
    __syncthreads();
    As[(lk0 + 0) * 68 + lm] = av.x;
    As[(lk0 + 1) * 68 + lm] = av.y;
    As[(lk0 + 2) * 68 + lm] = av.z;
    As[(lk0 + 3) * 68 + lm] = av.w;
    Bs[(lk0 + 0) * 68 + lm] = bv.x;
    Bs[(lk0 + 1) * 68 + lm] = bv.y;
    Bs[(lk0 + 2) * 68 + lm] = bv.z;
    Bs[(lk0 + 3) * 68 + lm] = bv.w;
    __syncthreads();
#pragma unroll
    for (int kk = 0; kk < 16; ++kk) {
      float4 a4 = *(const float4*)&As[kk * 68 + 4 * ty];
      float4 b4 = *(const float4*)&Bs[kk * 68 + 4 * tx];
      float a[4] = {a4.x, a4.y, a4.z, a4.w};
      float bl[4] = {b4.x, b4.y, b4.z, b4.w};
#pragma unroll
      for (int i = 0; i < 4; ++i)
#pragma unroll
        for (int j = 0; j < 4; ++j) acc[i][j] += a[i] * bl[j];
    }
  }

  const int comp = r0 / 384;
  const int hh = (r0 % 384) / 64;
  float* dst = ws + (size_t)comp * SZ;
  float4 bz = *(const float4*)&bias[r0 + 4 * tx];
#pragma unroll
  for (int i = 0; i < 4; ++i) {
    int m = m0 + 4 * ty + i;
    if (m >= MTOT) continue;
    int bb = m / NN, nn = m % NN;
    size_t base = (((size_t)(bb * NH + hh)) * NN + nn) * ND + 4 * tx;
    float4 o;
    o.x = acc[i][0] + bz.x;
    o.y = acc[i][1] + bz.y;
    o.z = acc[i][2] + bz.z;
    o.w = acc[i][3] + bz.w;
    *(float4*)&dst[base] = o;
  }
}

// ---------------------------------------------------------------------------
// Pack mask int32 -> bitmask (unchanged).
// ---------------------------------------------------------------------------
__global__ __launch_bounds__(256) void pack_mask_k(const int* __restrict__ mask,
                                                   unsigned* __restrict__ pm)
{
  const int wid = (blockIdx.x * 256 + threadIdx.x) >> 6;
  const int lane = threadIdx.x & 63;
  if (wid >= MTOT) return;
  const int* mr = mask + (size_t)wid * NN;
#pragma unroll
  for (int c = 0; c < 10; ++c) {
    int k = c * 64 + lane;
    int v = (k < NN) ? mr[k] : 0;
    unsigned long long bal = __ballot(v != 0);
    if (lane == 0) pm[wid * 20 + 2 * c] = (unsigned)bal;
    if (lane == 1) pm[wid * 20 + 2 * c + 1] = (unsigned)(bal >> 32);
  }
}

// ---------------------------------------------------------------------------
// Bias table: tbl[h][q][kk] = rel_pos[h][rel_idx[(q-1)*576 + kk-1]] as bf16,
// zeros for q==0 / kk==0 / kk>=577 / !patch_attn. Row stride 580 ushorts.
// ---------------------------------------------------------------------------
__global__ __launch_bounds__(256) void bias_build_k(
    const float* __restrict__ rel_pos, const int* __restrict__ rel_idx,
    const int* __restrict__ patch, unsigned short* __restrict__ tbl)
{
  const int q = blockIdx.x;          // 0..576
  const int h = blockIdx.y;          // 0..5
  const int pa = *patch;
  unsigned short* row = tbl + ((size_t)h * NN + q) * BSTRIDE;
  for (int kk = threadIdx.x; kk < BSTRIDE; kk += 256) {
    float v = 0.f;
    if (pa && q >= 1 && kk >= 1 && kk < NN)
      v = rel_pos[h * RPD2 + rel_idx[(q - 1) * 576 + (kk - 1)]];
    row[kk] = f2bf(v);
  }
}

// ---------------------------------------------------------------------------
// Flash attention with split-bf16 MFMA.
// Block = 256 threads (4 waves), 64 q-rows; wave w owns q rows 16w..16w+15.
// Per 64-key chunk: S^T = K*Q^T (lane holds one q = lane&15), bias via MFMA
// C-init, mask bits, online softmax in-register, P->LDS bf16, O += P*V.
// All LDS tiles XOR-swizzled: idx = row*64 + (col ^ ((row&7)<<3)).
// ---------------------------------------------------------------------------
__global__ __launch_bounds__(256, 2) void attn_k(
    const float* __restrict__ Q, const float* __restrict__ K,
    const float* __restrict__ V, float* __restrict__ O,
    const unsigned short* __restrict__ btbl, const unsigned* __restrict__ pmask)
{
  __shared__ unsigned short Qh[4096], Ql[4096];
  __shared__ unsigned short Kh[4096], Kl[4096];
  __shared__ unsigned short Vth[4096], Vtl[4096];
  __shared__ unsigned short Psh[4096], Psl[4096];
  __shared__ float frow[64], linv[64];

  const int tid = threadIdx.x;
  const int w = tid >> 6;          // wave 0..3
  const int l = tid & 63;          // lane
  const int lq = l & 15;
  const int lg = l >> 4;           // 0..3
  const int q0 = blockIdx.x * 64;
  const int h = blockIdx.y;
  const int b = blockIdx.z;
  const int bh = b * NH + h;
  const float* Qp = Q + (size_t)bh * NN * ND;
  const float* Kp = K + (size_t)bh * NN * ND;
  const float* Vp = V + (size_t)bh * NN * ND;

  // ---- stage Q (scaled, split) ----
  for (int u = tid; u < 1024; u += 256) {
    int q = u >> 4, d4 = (u & 15) << 2;
    int gq = q0 + q;
    float4 v = {0.f, 0.f, 0.f, 0.f};
    if (gq < NN) {
      v = *(const float4*)&Qp[(size_t)gq * ND + d4];
      v.x *= SCALE_; v.y *= SCALE_; v.z *= SCALE_; v.w *= SCALE_;
    }
    int idx = q * 64 + (d4 ^ ((q & 7) << 3));
    ushort4 hh, ll;
    hh.x = f2bf(v.x); ll.x = f2bf(v.x - bf2f(hh.x));
    hh.y = f2bf(v.y); ll.y = f2bf(v.y - bf2f(hh.y));
    hh.z = f2bf(v.z); ll.z = f2bf(v.z - bf2f(hh.z));
    hh.w = f2bf(v.w); ll.w = f2bf(v.w - bf2f(hh.w));
    *(ushort4*)&Qh[idx] = hh;
    *(ushort4*)&Ql[idx] = ll;
  }

  const int qrow = 16 * w + lq;          // this lane's q in QK/softmax phase
  const int gqA = q0 + qrow;
  const unsigned* pmrow = pmask + ((size_t)b * NN + (gqA < NN ? gqA : NN - 1)) * 20;
  const size_t brow = ((size_t)h * NN + (gqA < NN ? gqA : 0)) * BSTRIDE;

  float m_reg = NEGBIG, l_reg = 0.f;
  f32x4 accO[4] = {};

  for (int ch = 0; ch < 10; ++ch) {
    const int kbase = ch * 64;
    __syncthreads();   // A: prior PV reads done

    // ---- stage K (split, [key][d] swizzled) ----
    for (int u = tid; u < 1024; u += 256) {
      int key = u >> 4, d4 = (u & 15) << 2;
      int gk = kbase + key;
      float4 v = {0.f, 0.f, 0.f, 0.f};
      if (gk < NN) v = *(const float4*)&Kp[(size_t)gk * ND + d4];
      int idx = key * 64 + (d4 ^ ((key & 7) << 3));
      ushort4 hh, ll;
      hh.x = f2bf(v.x); ll.x = f2bf(v.x - bf2f(hh.x));
      hh.y = f2bf(v.y); ll.y = f2bf(v.y - bf2f(hh.y));
      hh.z = f2bf(v.z); ll.z = f2bf(v.z - bf2f(hh.z));
      hh.w = f2bf(v.w); ll.w = f2bf(v.w - bf2f(hh.w));
      *(ushort4*)&Kh[idx] = hh;
      *(ushort4*)&Kl[idx] = ll;
    }
    // ---- stage V transposed (split, [d][key] swizzled) ----
    for (int u = tid; u < 1024; u += 256) {
      int d = u & 63, k0 = (u >> 6) << 2;
      float v[4];
#pragma unroll
      for (int i = 0; i < 4; ++i) {
        int gk = kbase + k0 + i;
        v[i] = (gk < NN) ? Vp[(size_t)gk * ND + d] : 0.f;
      }
      int idx = d * 64 + (k0 ^ ((d & 7) << 3));
      ushort4 hh, ll;
      hh.x = f2bf(v[0]); ll.x = f2bf(v[0] - bf2f(hh.x));
      hh.y = f2bf(v[1]); ll.y = f2bf(v[1] - bf2f(hh.y));
      hh.z = f2bf(v[2]); ll.z = f2bf(v[2] - bf2f(hh.z));
      hh.w = f2bf(v[3]); ll.w = f2bf(v[3] - bf2f(hh.w));
      *(ushort4*)&Vth[idx] = hh;
      *(ushort4*)&Vtl[idx] = ll;
    }
    __syncthreads();   // B: K/V staged

    // ---- mask word for this lane's q, this chunk ----
    unsigned long long m64 =
        (unsigned long long)pmrow[2 * ch] |
        ((unsigned long long)pmrow[2 * ch + 1] << 32);

    // ---- Q B-fragments (shared across key tiles) ----
    bf16x8 qbh[2], qbl[2];
#pragma unroll
    for (int ks = 0; ks < 2; ++ks) {
      int idx = qrow * 64 + ((8 * lg + 32 * ks) ^ ((lq & 7) << 3));
      qbh[ks] = *(const bf16x8*)&Qh[idx];
      qbl[ks] = *(const bf16x8*)&Ql[idx];
    }

    // ---- S^T = K*Q^T with bias C-init ----
    float sv[4][4];
#pragma unroll
    for (int t = 0; t < 4; ++t) {
      f32x4 acc = {};
      int kkb = kbase + 16 * t + 4 * lg;
      if (gqA < NN && kkb <= 576) {
        ushort4 b4 = *(const ushort4*)&btbl[brow + kkb];
        acc[0] = bf2f(b4.x); acc[1] = bf2f(b4.y);
        acc[2] = bf2f(b4.z); acc[3] = bf2f(b4.w);
      }
#pragma unroll
      for (int ks = 0; ks < 2; ++ks) {
        int key16 = 16 * t + lq;
        int aidx = key16 * 64 + ((8 * lg + 32 * ks) ^ ((lq & 7) << 3));
        bf16x8 ah = *(const bf16x8*)&Kh[aidx];
        bf16x8 al = *(const bf16x8*)&Kl[aidx];
        acc = MFMA16(ah, qbh[ks], acc);
        acc = MFMA16(ah, qbl[ks], acc);
        acc = MFMA16(al, qbh[ks], acc);
      }
      sv[t][0] = acc[0]; sv[t][1] = acc[1];
      sv[t][2] = acc[2]; sv[t][3] = acc[3];
    }

    // ---- mask + online softmax (per-lane q) ----
    float cmax = NEGBIG;
#pragma unroll
    for (int t = 0; t < 4; ++t)
#pragma unroll
      for (int r = 0; r < 4; ++r) {
        int kl = 16 * t + 4 * lg + r;
        float s = ((m64 >> kl) & 1ull) ? sv[t][r] : NEGBIG;
        sv[t][r] = s;
        cmax = fmaxf(cmax, s);
      }
    cmax = fmaxf(cmax, __shfl_xor(cmax, 16));
    cmax = fmaxf(cmax, __shfl_xor(cmax, 32));
    float m_new = fmaxf(m_reg, cmax);
    float fx = __expf(m_reg - m_new);
    float csum = 0.f;
    float ev[4][4];
#pragma unroll
    for (int t = 0; t < 4; ++t)
#pragma unroll
      for (int r = 0; r < 4; ++r) {
        float e = __expf(sv[t][r] - m_new);
        ev[t][r] = e;
        csum += e;
      }
    csum += __shfl_xor(csum, 16);
    csum += __shfl_xor(csum, 32);
    l_reg = l_reg * fx + csum;
    m_reg = m_new;
    if (lg == 0) frow[qrow] = fx;

    // ---- pack P -> LDS (bf16 split, per-wave-private rows) ----
#pragma unroll
    for (int t = 0; t < 4; ++t) {
      ushort4 ph, pl;
      ph.x = f2bf(ev[t][0]); pl.x = f2bf(ev[t][0] - bf2f(ph.x));
      ph.y = f2bf(ev[t][1]); pl.y = f2bf(ev[t][1] - bf2f(ph.y));
      ph.z = f2bf(ev[t][2]); pl.z = f2bf(ev[t][2] - bf2f(ph.z));
      ph.w = f2bf(ev[t][3]); pl.w = f2bf(ev[t][3] - bf2f(ph.w));
      int pidx = qrow * 64 + ((16 * t + 4 * lg) ^ ((lq & 7) << 3));
      *(ushort4*)&Psh[pidx] = ph;
      *(ushort4*)&Psl[pidx] = pl;
    }
    __syncthreads();   // C: P/frow visible (also keeps waves phase-locked)

    // ---- O = O*f + P V ----
    float fx4[4];
#pragma unroll
    for (int r = 0; r < 4; ++r) fx4[r] = frow[16 * w + 4 * lg + r];
#pragma unroll
    for (int t = 0; t < 4; ++t) {
      accO[t][0] *= fx4[0]; accO[t][1] *= fx4[1];
      accO[t][2] *= fx4[2]; accO[t][3] *= fx4[3];
    }
    bf16x8 pah[2], pal[2];
#pragma unroll
    for (int ks = 0; ks < 2; ++ks) {
      int idx = qrow * 64 + ((8 * lg + 32 * ks) ^ ((lq & 7) << 3));
      pah[ks] = *(const bf16x8*)&Psh[idx];
      pal[ks] = *(const bf16x8*)&Psl[idx];
    }
#pragma unroll
    for (int t = 0; t < 4; ++t) {
#pragma unroll
      for (int ks = 0; ks < 2; ++ks) {
        int drow = 16 * t + lq;
        int vidx = drow * 64 + ((8 * lg + 32 * ks) ^ ((lq & 7) << 3));
        bf16x8 vh = *(const bf16x8*)&Vth[vidx];
        bf16x8 vl = *(const bf16x8*)&Vtl[vidx];
        accO[t] = MFMA16(pah[ks], vh, accO[t]);
        accO[t] = MFMA16(pal[ks], vh, accO[t]);
        accO[t] = MFMA16(pah[ks], vl, accO[t]);
      }
    }
  }

  if (lg == 0) linv[qrow] = 1.f / l_reg;
  __syncthreads();

  // ---- write O: lane holds (q = 16w + 4*lg + r, d = 16t + lq) ----
#pragma unroll
  for (int t = 0; t < 4; ++t)
#pragma unroll
    for (int r = 0; r < 4; ++r) {
      int gq = q0 + 16 * w + 4 * lg + r;
      if (gq < NN)
        O[((size_t)bh * NN + gq) * ND + 16 * t + lq] =
            accO[t][r] * linv[16 * w + 4 * lg + r];
    }
}

// ---------------------------------------------------------------------------
// Projection GEMM (fp32, unchanged).
// ---------------------------------------------------------------------------
__global__ __launch_bounds__(256) void proj_gemm_k(
    const float* __restrict__ O, const float* __restrict__ W,
    const float* __restrict__ bias, float* __restrict__ out)
{
  __shared__ float As[16 * 68];
  __shared__ float Bs[16 * 68];
  const int tid = threadIdx.x;
  const int m0 = blockIdx.x * 64;
  const int r0 = blockIdx.y * 64;
  const int tx = tid & 15, ty = tid >> 4;
  const int lm = tid >> 2, lk0 = (tid & 3) << 2;
  const int m = m0 + lm;
  const bool mv = m < MTOT;
  int bb = 0, nn = 0;
  if (mv) { bb = m / NN; nn = m % NN; }
  float acc[4][4] = {};

  for (int k0 = 0; k0 < 384; k0 += 16) {
    const int c = k0 + lk0;
    float4 av = {0.f, 0.f, 0.f, 0.f};
    if (mv) {
      int hh = c >> 6, d0 = c & 63;
      av = *(const float4*)&O[(((size_t)(bb * NH + hh)) * NN + nn) * ND + d0];
    }
    float4 bv = *(const float4*)&W[(size_t)(r0 + lm) * 384 + c];
    __syncthreads();
    As[(lk0 + 0) * 68 + lm] = av.x;
    As[(lk0 + 1) * 68 + lm] = av.y;
    As[(lk0 + 2) * 68 + lm] = av.z;
    As[(lk0 + 3) * 68 + lm] = av.w;
    Bs[(lk0 + 0) * 68 + lm] = bv.x;
    Bs[(lk0 + 1) * 68 + lm] = bv.y;
    Bs[(lk0 + 2) * 68 + lm] = bv.z;
    Bs[(lk0 + 3) * 68 + lm] = bv.w;
    __syncthreads();
#pragma unroll
    for (int kk = 0; kk < 16; ++kk) {
      float4 a4 = *(const float4*)&As[kk * 68 + 4 * ty];
      float4 b4 = *(const float4*)&Bs[kk * 68 + 4 * tx];
      float a[4] = {a4.x, a4.y, a4.z, a4.w};
      float bl[4] = {b4.x, b4.y, b4.z, b4.w};
#pragma unroll
      for (int i = 0; i < 4; ++i)
#pragma unroll
        for (int j = 0; j < 4; ++j) acc[i][j] += a[i] * bl[j];
    }
  }

  float4 bz = *(const float4*)&bias[r0 + 4 * tx];
#pragma unroll
  for (int i = 0; i < 4; ++i) {
    int mm = m0 + 4 * ty + i;
    if (mm >= MTOT) continue;
    float4 o;
    o.x = acc[i][0] + bz.x;
    o.y = acc[i][1] + bz.y;
    o.z = acc[i][2] + bz.z;
    o.w = acc[i][3] + bz.w;
    *(float4*)&out[(size_t)mm * NC + r0 + 4 * tx] = o;
  }
}

// ---------------------------------------------------------------------------
extern "C" void kernel_launch(void* const* d_in, const int* in_sizes, int n_in,
                              void* d_out, int out_size, void* d_ws, size_t ws_size,
                              hipStream_t stream) {
  const float* x       = (const float*)d_in[0];
  const float* qkv_w   = (const float*)d_in[1];
  const float* qkv_b   = (const float*)d_in[2];
  const float* proj_w  = (const float*)d_in[3];
  const float* proj_b  = (const float*)d_in[4];
  const float* rel_pos = (const float*)d_in[5];
  const int*   rel_idx = (const int*)d_in[6];
  const int*   mask    = (const int*)d_in[7];
  const int*   patch   = (const int*)d_in[8];
  float* out = (float*)d_out;
  float* ws  = (float*)d_ws;

  float* Qw = ws;
  float* Kw = ws + SZ;
  float* Vw = ws + 2 * SZ;
  float* Ow = ws + 3 * SZ;
  unsigned* pm = (unsigned*)(ws + 4 * SZ);                  // 9232*20 u32
  unsigned short* btbl = (unsigned short*)(pm + MTOT * 20); // 6*577*580 u16

  pack_mask_k<<<dim3((MTOT * 64 + 255) / 256), 256, 0, stream>>>(mask, pm);
  bias_build_k<<<dim3(NN, NH), 256, 0, stream>>>(rel_pos, rel_idx, patch, btbl);
  qkv_gemm_k<<<dim3(145, 18), 256, 0, stream>>>(x, qkv_w, qkv_b, ws);
  attn_k<<<dim3(10, NH, NB), 256, 0, stream>>>(Qw, Kw, Vw, Ow, btbl, pm);
  proj_gemm_k<<<dim3(145, 6), 256, 0, stream>>>(Ow, proj_w, proj_b, out);
}